// Round 7
// baseline (230.799 us; speedup 1.0000x reference)
//
#include <hip/hip_runtime.h>
#include <math.h>

// contracting REN forward. S=8, N=64, NU=6, NY=5, NH=80, B=524288.
// Outputs: hidden (B,8) then y (B,5), concatenated flat.

constexpr int NH = 80;

// ---- workspace layout (float offsets) ----
// main-kernel constants (C1F/D12F/BWF/DTT are pre-scaled by KAPPA=2*log2(e))
constexpr int WS_DTT  = 0;      // [64][64] j-major: DtT[j*64+i] = kappa*Dtilde[i][j]
constexpr int WS_C1F  = 4096;   // [64][8]
constexpr int WS_D12F = 4608;   // [64][6]
constexpr int WS_BWF  = 4992;   // [64]
constexpr int WS_G1   = 5056;   // [8][8]   Einv@F_
constexpr int WS_G2T  = 5120;   // [64][8]  (Einv@B1)^T, j-major
constexpr int WS_G3   = 5632;   // [8][6]   Einv@calB_2
constexpr int WS_G4   = 5680;   // [8]      Einv@bx
constexpr int WS_D21T = 5688;   // [64][5]  D21^T, j-major
// prep scratch
constexpr int WS_H    = 8192;   // [80][80]
constexpr int WS_EINV = 14600;  // [8][8]

__global__ void k_gram(const float* __restrict__ X, float* __restrict__ ws) {
    int idx = blockIdx.x * blockDim.x + threadIdx.x;
    if (idx >= NH * NH) return;
    int a = idx / NH, b = idx % NH;
    float acc = (a == b) ? 1e-4f : 0.f;
    for (int k = 0; k < NH; k++) acc += X[k * NH + a] * X[k * NH + b];
    ws[WS_H + idx] = acc;
}

__global__ void k_solve(const float* __restrict__ Y1, float* __restrict__ ws) {
    __shared__ float sM[8][17];
    __shared__ int sPiv;
    int tid = threadIdx.x;  // 128 threads
    const float* H = ws + WS_H;

    {
        int r = tid >> 4, c = tid & 15;
        sM[r][c] = (c < 8)
            ? 0.5f * (H[r * NH + c] + H[(72 + r) * NH + 72 + c] + Y1[r * 8 + c])
            : ((c - 8 == r) ? 1.f : 0.f);
    }
    __syncthreads();

    for (int p = 0; p < 8; p++) {
        if (tid == 0) {
            int pr = p; float best = fabsf(sM[p][p]);
            for (int r = p + 1; r < 8; r++) {
                float v = fabsf(sM[r][p]);
                if (v > best) { best = v; pr = r; }
            }
            sPiv = pr;
        }
        __syncthreads();
        int pr = sPiv;
        if (pr != p && tid < 16) { float tv = sM[p][tid]; sM[p][tid] = sM[pr][tid]; sM[pr][tid] = tv; }
        __syncthreads();
        if (tid < 16) {
            float inv = 1.f / sM[p][p];
            sM[p][tid] *= inv;
        }
        __syncthreads();
        int r = tid >> 4, c = tid & 15;
        float f = sM[r][p], pc = sM[p][c];
        __syncthreads();
        if (r != p) sM[r][c] -= f * pc;
        __syncthreads();
    }
    if (tid < 64) ws[WS_EINV + tid] = sM[tid >> 3][8 + (tid & 7)];
}

__global__ void k_finish(const float* __restrict__ calB2,
                         const float* __restrict__ calD12,
                         const float* __restrict__ D21,
                         const float* __restrict__ bias,
                         float* __restrict__ ws) {
    __shared__ float srL[64];    // 1/Lambda
    __shared__ float sEinv[64];
    int tid = threadIdx.x;  // 256
    const float* H = ws + WS_H;
    const float KAPPA = 2.8853900817779268f;  // 2*log2(e)

    if (tid < 64) srL[tid] = 2.0f / H[(8 + tid) * NH + 8 + tid];
    else if (tid < 128) sEinv[tid - 64] = ws[WS_EINV + tid - 64];
    __syncthreads();

    // DtT[j][i] = -kappa * H22[i][j] / lam[i] for i>j else 0
    for (int idx = tid; idx < 4096; idx += 256) {
        int j = idx >> 6, i = idx & 63;
        ws[WS_DTT + idx] = (i > j) ? -KAPPA * H[(8 + i) * NH + 8 + j] * srL[i] : 0.f;
    }
    // C1f[i][s] = -kappa * H[8+i][s] / lam[i]
    for (int idx = tid; idx < 512; idx += 256) {
        int i = idx >> 3, s2 = idx & 7;
        ws[WS_C1F + idx] = -KAPPA * H[(8 + i) * NH + s2] * srL[i];
    }
    // D12f = kappa * calD_12 / lam
    for (int idx = tid; idx < 384; idx += 256) {
        int i = idx / 6;
        ws[WS_D12F + idx] = KAPPA * calD12[idx] * srL[i];
    }
    if (tid < 64) ws[WS_BWF + tid] = KAPPA * bias[8 + tid] * srL[tid];
    // G1 = Einv @ F_
    if (tid < 64) {
        int a = tid >> 3, s2 = tid & 7; float acc = 0.f;
        for (int k = 0; k < 8; k++) acc += sEinv[a * 8 + k] * H[(72 + k) * NH + s2];
        ws[WS_G1 + tid] = acc;
    }
    // G2T[j][a] = (Einv @ B1)[a][j]
    for (int idx = tid; idx < 512; idx += 256) {
        int j = idx >> 3, a = idx & 7; float acc = 0.f;
        for (int k = 0; k < 8; k++) acc += sEinv[a * 8 + k] * H[(72 + k) * NH + 8 + j];
        ws[WS_G2T + idx] = acc;
    }
    // G3 = Einv @ calB_2
    if (tid < 48) {
        int a = tid / 6, c = tid % 6; float acc = 0.f;
        for (int k = 0; k < 8; k++) acc += sEinv[a * 8 + k] * calB2[k * 6 + c];
        ws[WS_G3 + tid] = acc;
    }
    // g4 = Einv @ bx
    if (tid < 8) {
        float acc = 0.f;
        for (int k = 0; k < 8; k++) acc += sEinv[tid * 8 + k] * bias[k];
        ws[WS_G4 + tid] = acc;
    }
    // D21T[j][q] = D21[q][j]
    for (int idx = tid; idx < 320; idx += 256) {
        int j = idx / 5, q = idx % 5;
        ws[WS_D21T + idx] = D21[q * 64 + j];
    }
}

// q = 2*log2(e)*v  ->  tanh(v) = 1 - 2/(1+2^q).  No clamp needed:
// exp2(+big)=inf -> rcp=0 -> +1 ; exp2(-big)=0 -> rcp(1)=1 -> -1.
__device__ __forceinline__ float tanh_scaled(float q) {
    float e = __builtin_amdgcn_exp2f(q);
    return 1.f - 2.f * __builtin_amdgcn_rcpf(1.f + e);
}

// ---- forced full unroll via template recursion: every index is a
// compile-time constant, so v[]/h[]/y[] MUST promote to VGPRs (no scratch).
template<int I>
struct Init {
    static __device__ __forceinline__ void run(float (&v)[64], const float (&x)[8],
                                               const float (&u)[6], const float* __restrict__ ws) {
        float A = ws[WS_BWF + I];
        #pragma unroll
        for (int s2 = 0; s2 < 8; s2++) A += x[s2] * ws[WS_C1F + I * 8 + s2];
        #pragma unroll
        for (int c2 = 0; c2 < 6; c2++) A += u[c2] * ws[WS_D12F + I * 6 + c2];
        v[I] = A;
        Init<I + 1>::run(v, x, u, ws);
    }
};
template<> struct Init<64> {
    static __device__ __forceinline__ void run(float (&)[64], const float (&)[8],
                                               const float (&)[6], const float* __restrict__) {}
};

template<int J>
struct Step {
    static __device__ __forceinline__ void run(float (&v)[64], float (&h)[8], float (&y)[5],
                                               const float* __restrict__ ws) {
        float ta = tanh_scaled(v[J]);
        #pragma unroll
        for (int i = J + 1; i < 64; i++) v[i] += ws[WS_DTT + J * 64 + i] * ta;
        #pragma unroll
        for (int a = 0; a < 8; a++) h[a] += ws[WS_G2T + J * 8 + a] * ta;
        #pragma unroll
        for (int q = 0; q < 5; q++) y[q] += ws[WS_D21T + J * 5 + q] * ta;
        Step<J + 1>::run(v, h, y, ws);
    }
};
template<> struct Step<64> {
    static __device__ __forceinline__ void run(float (&)[64], float (&)[8], float (&)[5],
                                               const float* __restrict__) {}
};

__global__ __launch_bounds__(256, 2) void k_main(
    const float* __restrict__ xg, const float* __restrict__ ug,
    const float* __restrict__ C2, const float* __restrict__ D22,
    const float* __restrict__ bias, const float* __restrict__ ws,
    float* __restrict__ out, int B)
{
    int t = blockIdx.x * 256 + threadIdx.x;
    if (t >= B) return;

    float xv[8], uv[6];
    {
        const float4* xp = reinterpret_cast<const float4*>(xg + (size_t)t * 8);
        float4 a0 = xp[0], a1 = xp[1];
        xv[0]=a0.x; xv[1]=a0.y; xv[2]=a0.z; xv[3]=a0.w;
        xv[4]=a1.x; xv[5]=a1.y; xv[6]=a1.z; xv[7]=a1.w;
        const float2* up = reinterpret_cast<const float2*>(ug + (size_t)t * 6);
        float2 c0 = up[0], c1 = up[1], c2 = up[2];
        uv[0]=c0.x; uv[1]=c0.y; uv[2]=c1.x; uv[3]=c1.y; uv[4]=c2.x; uv[5]=c2.y;
    }

    // v0 in kappa-scaled units (bw, 1/Lambda, kappa folded)
    float v[64];
    Init<0>::run(v, xv, uv, ws);

    // pre-accumulate x/u parts of outputs (x,u die here)
    float h[8];
    #pragma unroll
    for (int a = 0; a < 8; a++) {
        float A = ws[WS_G4 + a];
        #pragma unroll
        for (int s2 = 0; s2 < 8; s2++) A += xv[s2] * ws[WS_G1 + a * 8 + s2];
        #pragma unroll
        for (int c2 = 0; c2 < 6; c2++) A += uv[c2] * ws[WS_G3 + a * 6 + c2];
        h[a] = A;
    }
    float y[5];
    #pragma unroll
    for (int q = 0; q < 5; q++) {
        float A = bias[72 + q];
        #pragma unroll
        for (int s2 = 0; s2 < 8; s2++) A += xv[s2] * C2[q * 8 + s2];
        #pragma unroll
        for (int c2 = 0; c2 < 6; c2++) A += uv[c2] * D22[q * 6 + c2];
        y[q] = A;
    }

    // scatter-form tanh scan; all updates at step J are independent FMAs
    Step<0>::run(v, h, y, ws);

    float4* hp = reinterpret_cast<float4*>(out + (size_t)t * 8);
    hp[0] = make_float4(h[0], h[1], h[2], h[3]);
    hp[1] = make_float4(h[4], h[5], h[6], h[7]);

    float* yp = out + (size_t)B * 8 + (size_t)t * 5;
    #pragma unroll
    for (int q = 0; q < 5; q++) yp[q] = y[q];
}

extern "C" void kernel_launch(void* const* d_in, const int* in_sizes, int n_in,
                              void* d_out, int out_size, void* d_ws, size_t ws_size,
                              hipStream_t stream) {
    const float* x      = (const float*)d_in[0];
    const float* u      = (const float*)d_in[1];
    const float* X      = (const float*)d_in[2];
    const float* calB2  = (const float*)d_in[3];
    const float* C2     = (const float*)d_in[4];
    const float* calD12 = (const float*)d_in[5];
    const float* D21    = (const float*)d_in[6];
    const float* D22    = (const float*)d_in[7];
    const float* Y1     = (const float*)d_in[8];
    const float* bias   = (const float*)d_in[9];
    float* ws  = (float*)d_ws;
    float* out = (float*)d_out;
    int B = in_sizes[0] / 8;

    k_gram  <<<(NH * NH + 255) / 256, 256, 0, stream>>>(X, ws);
    k_solve <<<1, 128, 0, stream>>>(Y1, ws);
    k_finish<<<1, 256, 0, stream>>>(calB2, calD12, D21, bias, ws);
    k_main  <<<(B + 255) / 256, 256, 0, stream>>>(x, u, C2, D22, bias, ws, out, B);
}

// Round 9
// 154.731 us; speedup vs baseline: 1.4916x; 1.4916x over previous
//
#include <hip/hip_runtime.h>
#include <math.h>

// contracting REN forward. S=8, N=64, NU=6, NY=5, NH=80, B=524288.
// Outputs: hidden (B,8) then y (B,5), concatenated flat.
// k_main uses R1's proven loop shape (plain unrolled loops, gather form,
// 1 row/thread, launch_bounds(256)) — the only shape hipcc promoted to VGPRs.

constexpr int NH = 80;

// ---- workspace layout (float offsets) ----
// C1F/D12F/BWF/DTT are pre-scaled by KAPPA=2*log2(e) for exp2-based tanh.
constexpr int WS_DTT  = 0;      // [64][64] i-major: DTT[i*64+j] = kappa*Dtilde[i][j] (j<i)
constexpr int WS_C1F  = 4096;   // [64][8]
constexpr int WS_D12F = 4608;   // [64][6]
constexpr int WS_BWF  = 4992;   // [64]
constexpr int WS_G1   = 5056;   // [8][8]   Einv@F_
constexpr int WS_G2   = 5120;   // [8][64]  Einv@B1, a-major
constexpr int WS_G3   = 5632;   // [8][6]   Einv@calB_2
constexpr int WS_G4   = 5680;   // [8]      Einv@bx
// prep scratch
constexpr int WS_H    = 8192;   // [80][80]
constexpr int WS_EINV = 14600;  // [8][8]

__global__ void k_gram(const float* __restrict__ X, float* __restrict__ ws) {
    int idx = blockIdx.x * blockDim.x + threadIdx.x;
    if (idx >= NH * NH) return;
    int a = idx / NH, b = idx % NH;
    float acc = (a == b) ? 1e-4f : 0.f;
    for (int k = 0; k < NH; k++) acc += X[k * NH + a] * X[k * NH + b];
    ws[WS_H + idx] = acc;
}

__global__ void k_solve(const float* __restrict__ Y1, float* __restrict__ ws) {
    __shared__ float sM[8][17];
    __shared__ int sPiv;
    int tid = threadIdx.x;  // 128 threads
    const float* H = ws + WS_H;

    {
        int r = tid >> 4, c = tid & 15;
        sM[r][c] = (c < 8)
            ? 0.5f * (H[r * NH + c] + H[(72 + r) * NH + 72 + c] + Y1[r * 8 + c])
            : ((c - 8 == r) ? 1.f : 0.f);
    }
    __syncthreads();

    for (int p = 0; p < 8; p++) {
        if (tid == 0) {
            int pr = p; float best = fabsf(sM[p][p]);
            for (int r = p + 1; r < 8; r++) {
                float v = fabsf(sM[r][p]);
                if (v > best) { best = v; pr = r; }
            }
            sPiv = pr;
        }
        __syncthreads();
        int pr = sPiv;
        if (pr != p && tid < 16) { float tv = sM[p][tid]; sM[p][tid] = sM[pr][tid]; sM[pr][tid] = tv; }
        __syncthreads();
        if (tid < 16) {
            float inv = 1.f / sM[p][p];
            sM[p][tid] *= inv;
        }
        __syncthreads();
        int r = tid >> 4, c = tid & 15;
        float f = sM[r][p], pc = sM[p][c];
        __syncthreads();
        if (r != p) sM[r][c] -= f * pc;
        __syncthreads();
    }
    if (tid < 64) ws[WS_EINV + tid] = sM[tid >> 3][8 + (tid & 7)];
}

__global__ void k_finish(const float* __restrict__ calB2,
                         const float* __restrict__ calD12,
                         const float* __restrict__ bias,
                         float* __restrict__ ws) {
    __shared__ float srL[64];    // 1/Lambda
    __shared__ float sEinv[64];
    int tid = threadIdx.x;  // 256
    const float* H = ws + WS_H;
    const float KAPPA = 2.8853900817779268f;  // 2*log2(e)

    if (tid < 64) srL[tid] = 2.0f / H[(8 + tid) * NH + 8 + tid];
    else if (tid < 128) sEinv[tid - 64] = ws[WS_EINV + tid - 64];
    __syncthreads();

    // DTT[i][j] = -kappa * H22[i][j] / lam[i] for j<i else 0   (i-major, gather)
    for (int idx = tid; idx < 4096; idx += 256) {
        int i = idx >> 6, j = idx & 63;
        ws[WS_DTT + idx] = (j < i) ? -KAPPA * H[(8 + i) * NH + 8 + j] * srL[i] : 0.f;
    }
    // C1f[i][s] = -kappa * H[8+i][s] / lam[i]
    for (int idx = tid; idx < 512; idx += 256) {
        int i = idx >> 3, s2 = idx & 7;
        ws[WS_C1F + idx] = -KAPPA * H[(8 + i) * NH + s2] * srL[i];
    }
    // D12f = kappa * calD_12 / lam
    for (int idx = tid; idx < 384; idx += 256) {
        int i = idx / 6;
        ws[WS_D12F + idx] = KAPPA * calD12[idx] * srL[i];
    }
    if (tid < 64) ws[WS_BWF + tid] = KAPPA * bias[8 + tid] * srL[tid];
    // G1 = Einv @ F_
    if (tid < 64) {
        int a = tid >> 3, s2 = tid & 7; float acc = 0.f;
        for (int k = 0; k < 8; k++) acc += sEinv[a * 8 + k] * H[(72 + k) * NH + s2];
        ws[WS_G1 + tid] = acc;
    }
    // G2[a][j] = (Einv @ B1)[a][j]   (a-major, gather)
    for (int idx = tid; idx < 512; idx += 256) {
        int a = idx >> 6, j = idx & 63; float acc = 0.f;
        for (int k = 0; k < 8; k++) acc += sEinv[a * 8 + k] * H[(72 + k) * NH + 8 + j];
        ws[WS_G2 + idx] = acc;
    }
    // G3 = Einv @ calB_2
    if (tid < 48) {
        int a = tid / 6, c = tid % 6; float acc = 0.f;
        for (int k = 0; k < 8; k++) acc += sEinv[a * 8 + k] * calB2[k * 6 + c];
        ws[WS_G3 + tid] = acc;
    }
    // g4 = Einv @ bx
    if (tid < 8) {
        float acc = 0.f;
        for (int k = 0; k < 8; k++) acc += sEinv[tid * 8 + k] * bias[k];
        ws[WS_G4 + tid] = acc;
    }
}

// q = 2*log2(e)*v  ->  tanh(v) = 1 - 2/(1+2^q).  No clamp needed:
// exp2(+big)=inf -> rcp(inf)=0 -> +1 ; exp2(-big)=0 -> rcp(1)=1 -> -1.
__device__ __forceinline__ float tanh_scaled(float q) {
    float e = __builtin_amdgcn_exp2f(q);
    return 1.f - 2.f * __builtin_amdgcn_rcpf(1.f + e);
}

__global__ __launch_bounds__(256) void k_main(
    const float* __restrict__ xg, const float* __restrict__ ug,
    const float* __restrict__ C2, const float* __restrict__ D21,
    const float* __restrict__ D22, const float* __restrict__ bias,
    const float* __restrict__ ws, float* __restrict__ out, int B)
{
    int t = blockIdx.x * blockDim.x + threadIdx.x;
    if (t >= B) return;

    float xv[8], uv[6];
    {
        const float4* xp = reinterpret_cast<const float4*>(xg + (size_t)t * 8);
        float4 a0 = xp[0], a1 = xp[1];
        xv[0]=a0.x; xv[1]=a0.y; xv[2]=a0.z; xv[3]=a0.w;
        xv[4]=a1.x; xv[5]=a1.y; xv[6]=a1.z; xv[7]=a1.w;
        const float2* up = reinterpret_cast<const float2*>(ug + (size_t)t * 6);
        float2 c0 = up[0], c1 = up[1], c2 = up[2];
        uv[0]=c0.x; uv[1]=c0.y; uv[2]=c1.x; uv[3]=c1.y; uv[4]=c2.x; uv[5]=c2.y;
    }

    const float* C1f  = ws + WS_C1F;
    const float* D12f = ws + WS_D12F;
    const float* bwf  = ws + WS_BWF;
    const float* Dt   = ws + WS_DTT;
    const float* G1   = ws + WS_G1;
    const float* G2   = ws + WS_G2;
    const float* G3   = ws + WS_G3;
    const float* g4   = ws + WS_G4;

    // v0 in kappa-scaled units (bw, 1/Lambda, kappa folded)
    float w[64];
    #pragma unroll
    for (int i = 0; i < 64; i++) {
        float acc = bwf[i];
        #pragma unroll
        for (int s2 = 0; s2 < 8; s2++) acc += xv[s2] * C1f[i * 8 + s2];
        #pragma unroll
        for (int c2 = 0; c2 < 6; c2++) acc += uv[c2] * D12f[i * 6 + c2];
        w[i] = acc;
    }

    // gather-form triangular tanh scan, 4-way partial sums to break chains
    #pragma unroll
    for (int i = 0; i < 64; i++) {
        float a0 = w[i], a1 = 0.f, a2 = 0.f, a3 = 0.f;
        #pragma unroll
        for (int j = 0; j + 3 < i; j += 4) {
            a0 += Dt[i * 64 + j    ] * w[j    ];
            a1 += Dt[i * 64 + j + 1] * w[j + 1];
            a2 += Dt[i * 64 + j + 2] * w[j + 2];
            a3 += Dt[i * 64 + j + 3] * w[j + 3];
        }
        #pragma unroll
        for (int j = i & ~3; j < i; j++)
            a1 += Dt[i * 64 + j] * w[j];
        w[i] = tanh_scaled((a0 + a1) + (a2 + a3));
    }

    // hidden = x@G1.T + w@G2.T + u@G3.T + g4   (Einv folded)
    float h[8];
    #pragma unroll
    for (int a = 0; a < 8; a++) {
        float acc = g4[a];
        #pragma unroll
        for (int s2 = 0; s2 < 8; s2++) acc += xv[s2] * G1[a * 8 + s2];
        #pragma unroll
        for (int c2 = 0; c2 < 6; c2++) acc += uv[c2] * G3[a * 6 + c2];
        #pragma unroll
        for (int j = 0; j < 64; j++) acc += w[j] * G2[a * 64 + j];
        h[a] = acc;
    }
    float4* hp = reinterpret_cast<float4*>(out + (size_t)t * 8);
    hp[0] = make_float4(h[0], h[1], h[2], h[3]);
    hp[1] = make_float4(h[4], h[5], h[6], h[7]);

    // y = x@C2.T + w@D21.T + u@D22.T + by
    float* yp = out + (size_t)B * 8 + (size_t)t * 5;
    #pragma unroll
    for (int q = 0; q < 5; q++) {
        float acc = bias[72 + q];
        #pragma unroll
        for (int s2 = 0; s2 < 8; s2++) acc += xv[s2] * C2[q * 8 + s2];
        #pragma unroll
        for (int c2 = 0; c2 < 6; c2++) acc += uv[c2] * D22[q * 6 + c2];
        #pragma unroll
        for (int j = 0; j < 64; j++) acc += w[j] * D21[q * 64 + j];
        yp[q] = acc;
    }
}

extern "C" void kernel_launch(void* const* d_in, const int* in_sizes, int n_in,
                              void* d_out, int out_size, void* d_ws, size_t ws_size,
                              hipStream_t stream) {
    const float* x      = (const float*)d_in[0];
    const float* u      = (const float*)d_in[1];
    const float* X      = (const float*)d_in[2];
    const float* calB2  = (const float*)d_in[3];
    const float* C2     = (const float*)d_in[4];
    const float* calD12 = (const float*)d_in[5];
    const float* D21    = (const float*)d_in[6];
    const float* D22    = (const float*)d_in[7];
    const float* Y1     = (const float*)d_in[8];
    const float* bias   = (const float*)d_in[9];
    float* ws  = (float*)d_ws;
    float* out = (float*)d_out;
    int B = in_sizes[0] / 8;

    k_gram  <<<(NH * NH + 255) / 256, 256, 0, stream>>>(X, ws);
    k_solve <<<1, 128, 0, stream>>>(Y1, ws);
    k_finish<<<1, 256, 0, stream>>>(calB2, calD12, bias, ws);
    k_main  <<<(B + 255) / 256, 256, 0, stream>>>(x, u, C2, D21, D22, bias, ws, out, B);
}

// Round 11
// 77.859 us; speedup vs baseline: 2.9643x; 1.9873x over previous
//
#include <hip/hip_runtime.h>
#include <hip/hip_fp16.h>
#include <math.h>

// contracting REN forward. S=8, N=64, NU=6, NY=5, NH=80, B=524288.
// Outputs: hidden (B,8) then y (B,5), concatenated flat.
// R10: f16-packed constants + v_dot2_f32_f16 (2 MAC/instr, fp32 accum),
// w/v0 packed into uint sv[32] (whole-register writes only) to cut live
// VGPRs below the 64-reg occupancy quantum (8 waves/SIMD).

constexpr int NH = 80;

// ---- workspace layout (float/uint offsets into ws) ----
constexpr int WS_DTT2 = 0;      // uint[64*32]  packed f16 pairs: kappa*Dt[i][2p],[2p+1] (j<i else 0)
constexpr int WS_V0C  = 2048;   // uint[64*8]   per i: 4 C1 pairs, 3 D12 pairs, 1 zero (kappa-scaled)
constexpr int WS_G2P  = 2560;   // uint[8*32]   (Einv@B1)[a] packed pairs
constexpr int WS_D21P = 2816;   // uint[5*32]   D21[q] packed pairs
constexpr int WS_BWF  = 2976;   // float[64]    kappa*bw/Lambda
constexpr int WS_G1   = 3040;   // float[8*8]   Einv@F_
constexpr int WS_G3   = 3104;   // float[8*6]   Einv@calB_2
constexpr int WS_G4   = 3152;   // float[8]     Einv@bx
constexpr int WS_C2W  = 3160;   // float[5*8]   C2 copy
constexpr int WS_D22W = 3200;   // float[5*6]   D22 copy
constexpr int WS_BY   = 3232;   // float[5]     by copy
// prep scratch
constexpr int WS_H    = 4096;   // float[80*80]
constexpr int WS_EINV = 10496;  // float[8*8]

__device__ __forceinline__ unsigned pack_rn(float a, float b) {
    unsigned lo = __half_as_ushort(__float2half(a));
    unsigned hi = __half_as_ushort(__float2half(b));
    return lo | (hi << 16);
}

typedef _Float16 h2 __attribute__((ext_vector_type(2)));

__device__ __forceinline__ float dot2(unsigned c, unsigned w, float acc) {
#if __has_builtin(__builtin_amdgcn_fdot2)
    return __builtin_amdgcn_fdot2(__builtin_bit_cast(h2, c),
                                  __builtin_bit_cast(h2, w), acc, false);
#else
    float out;
    asm("v_dot2_f32_f16 %0, %1, %2, %3" : "=v"(out) : "v"(c), "v"(w), "0"(acc));
    return out;
#endif
}
__device__ __forceinline__ float lo_f(unsigned u) { return (float)__builtin_bit_cast(h2, u).x; }
__device__ __forceinline__ float hi_f(unsigned u) { return (float)__builtin_bit_cast(h2, u).y; }

__global__ void k_gram(const float* __restrict__ X, float* __restrict__ ws) {
    int idx = blockIdx.x * blockDim.x + threadIdx.x;
    if (idx >= NH * NH) return;
    int a = idx / NH, b = idx % NH;
    float acc = (a == b) ? 1e-4f : 0.f;
    for (int k = 0; k < NH; k++) acc += X[k * NH + a] * X[k * NH + b];
    ws[WS_H + idx] = acc;
}

__global__ void k_solve(const float* __restrict__ Y1, float* __restrict__ ws) {
    __shared__ float sM[8][17];
    __shared__ int sPiv;
    int tid = threadIdx.x;  // 128 threads
    const float* H = ws + WS_H;
    {
        int r = tid >> 4, c = tid & 15;
        sM[r][c] = (c < 8)
            ? 0.5f * (H[r * NH + c] + H[(72 + r) * NH + 72 + c] + Y1[r * 8 + c])
            : ((c - 8 == r) ? 1.f : 0.f);
    }
    __syncthreads();
    for (int p = 0; p < 8; p++) {
        if (tid == 0) {
            int pr = p; float best = fabsf(sM[p][p]);
            for (int r = p + 1; r < 8; r++) {
                float v = fabsf(sM[r][p]);
                if (v > best) { best = v; pr = r; }
            }
            sPiv = pr;
        }
        __syncthreads();
        int pr = sPiv;
        if (pr != p && tid < 16) { float tv = sM[p][tid]; sM[p][tid] = sM[pr][tid]; sM[pr][tid] = tv; }
        __syncthreads();
        if (tid < 16) {
            float inv = 1.f / sM[p][p];
            sM[p][tid] *= inv;
        }
        __syncthreads();
        int r = tid >> 4, c = tid & 15;
        float f = sM[r][p], pc = sM[p][c];
        __syncthreads();
        if (r != p) sM[r][c] -= f * pc;
        __syncthreads();
    }
    if (tid < 64) ws[WS_EINV + tid] = sM[tid >> 3][8 + (tid & 7)];
}

__global__ void k_finish(const float* __restrict__ calB2,
                         const float* __restrict__ calD12,
                         const float* __restrict__ C2,
                         const float* __restrict__ D21,
                         const float* __restrict__ D22,
                         const float* __restrict__ bias,
                         float* ws) {
    __shared__ float srL[64];
    __shared__ float sEinv[64];
    int tid = threadIdx.x;  // 256
    const float* H = ws + WS_H;
    unsigned* wsu = (unsigned*)ws;
    const float KAPPA = 2.8853900817779268f;  // 2*log2(e)

    if (tid < 64) srL[tid] = 2.0f / H[(8 + tid) * NH + 8 + tid];
    else if (tid < 128) sEinv[tid - 64] = ws[WS_EINV + tid - 64];
    __syncthreads();

    // DTT2: packed kappa*Dt rows (j<i else 0)
    for (int idx = tid; idx < 2048; idx += 256) {
        int i = idx >> 5, p = idx & 31;
        int j0 = 2 * p, j1 = 2 * p + 1;
        float f0 = (j0 < i) ? -KAPPA * H[(8 + i) * NH + 8 + j0] * srL[i] : 0.f;
        float f1 = (j1 < i) ? -KAPPA * H[(8 + i) * NH + 8 + j1] * srL[i] : 0.f;
        wsu[WS_DTT2 + idx] = pack_rn(f0, f1);
    }
    // V0C: per-row packed C1 (4 pairs) + D12 (3 pairs) + zero
    for (int idx = tid; idx < 512; idx += 256) {
        int i = idx >> 3, c = idx & 7;
        float f0 = 0.f, f1 = 0.f;
        if (c < 4) {
            f0 = -KAPPA * H[(8 + i) * NH + 2 * c] * srL[i];
            f1 = -KAPPA * H[(8 + i) * NH + 2 * c + 1] * srL[i];
        } else if (c < 7) {
            int d = 2 * (c - 4);
            f0 = KAPPA * calD12[i * 6 + d] * srL[i];
            f1 = KAPPA * calD12[i * 6 + d + 1] * srL[i];
        }
        wsu[WS_V0C + idx] = pack_rn(f0, f1);
    }
    // G2P = packed (Einv @ B1)
    for (int idx = tid; idx < 256; idx += 256) {
        int a = idx >> 5, p = idx & 31;
        float g0 = 0.f, g1 = 0.f;
        for (int k = 0; k < 8; k++) {
            g0 += sEinv[a * 8 + k] * H[(72 + k) * NH + 8 + 2 * p];
            g1 += sEinv[a * 8 + k] * H[(72 + k) * NH + 8 + 2 * p + 1];
        }
        wsu[WS_G2P + idx] = pack_rn(g0, g1);
    }
    // D21P packed
    for (int idx = tid; idx < 160; idx += 256) {
        int q = idx / 32, p = idx % 32;
        wsu[WS_D21P + idx] = pack_rn(D21[q * 64 + 2 * p], D21[q * 64 + 2 * p + 1]);
    }
    if (tid < 64) ws[WS_BWF + tid] = KAPPA * bias[8 + tid] * srL[tid];
    if (tid < 64) {
        int a = tid >> 3, s = tid & 7; float acc = 0.f;
        for (int k = 0; k < 8; k++) acc += sEinv[a * 8 + k] * H[(72 + k) * NH + s];
        ws[WS_G1 + tid] = acc;
    }
    if (tid < 48) {
        int a = tid / 6, c = tid % 6; float acc = 0.f;
        for (int k = 0; k < 8; k++) acc += sEinv[a * 8 + k] * calB2[k * 6 + c];
        ws[WS_G3 + tid] = acc;
    }
    if (tid < 8) {
        float acc = 0.f;
        for (int k = 0; k < 8; k++) acc += sEinv[tid * 8 + k] * bias[k];
        ws[WS_G4 + tid] = acc;
    }
    if (tid < 40) ws[WS_C2W + tid] = C2[tid];
    if (tid < 30) ws[WS_D22W + tid] = D22[tid];
    if (tid < 5)  ws[WS_BY + tid]  = bias[72 + tid];
}

// acc already kappa-scaled: tanh(v) = 1 - 2/(1+2^q). No clamp needed:
// exp2(+big)=inf -> rcp=0 -> +1 ; exp2(-big)=0 -> rcp(1)=1 -> -1.
__device__ __forceinline__ float tanh_scaled(float q) {
    float e = __builtin_amdgcn_exp2f(q);
    return 1.f - 2.f * __builtin_amdgcn_rcpf(1.f + e);
}

__global__ __launch_bounds__(256) void k_main(
    const float* __restrict__ xg, const float* __restrict__ ug,
    const float* __restrict__ ws, float* __restrict__ out, int B)
{
    int t = blockIdx.x * blockDim.x + threadIdx.x;
    if (t >= B) return;

    const unsigned* wsu = (const unsigned*)ws;

    float xv[8], uv[6];
    {
        const float4* xp = reinterpret_cast<const float4*>(xg + (size_t)t * 8);
        float4 a0 = xp[0], a1 = xp[1];
        xv[0]=a0.x; xv[1]=a0.y; xv[2]=a0.z; xv[3]=a0.w;
        xv[4]=a1.x; xv[5]=a1.y; xv[6]=a1.z; xv[7]=a1.w;
        const float2* up = reinterpret_cast<const float2*>(ug + (size_t)t * 6);
        float2 c0 = up[0], c1 = up[1], c2 = up[2];
        uv[0]=c0.x; uv[1]=c0.y; uv[2]=c1.x; uv[3]=c1.y; uv[4]=c2.x; uv[5]=c2.y;
    }
    // packed copies of x,u for the f16 dot2 init
    unsigned xh[4], uh[3];
    #pragma unroll
    for (int c = 0; c < 4; c++) xh[c] = pack_rn(xv[2 * c], xv[2 * c + 1]);
    #pragma unroll
    for (int c = 0; c < 3; c++) uh[c] = pack_rn(uv[2 * c], uv[2 * c + 1]);

    // v0 pairs (kappa-scaled), packed into sv
    unsigned sv[32];
    #pragma unroll
    for (int k = 0; k < 32; k++) {
        float a0 = ws[WS_BWF + 2 * k];
        float a1 = ws[WS_BWF + 2 * k + 1];
        #pragma unroll
        for (int c = 0; c < 4; c++) {
            a0 = dot2(wsu[WS_V0C + (2 * k) * 8 + c],     xh[c], a0);
            a1 = dot2(wsu[WS_V0C + (2 * k + 1) * 8 + c], xh[c], a1);
        }
        #pragma unroll
        for (int c = 0; c < 3; c++) {
            a0 = dot2(wsu[WS_V0C + (2 * k) * 8 + 4 + c],     uh[c], a0);
            a1 = dot2(wsu[WS_V0C + (2 * k + 1) * 8 + 4 + c], uh[c], a1);
        }
        sv[k] = pack_rn(a0, a1);
    }

    // pre-accumulate x/u parts of outputs (x,u die here)
    float h[8];
    #pragma unroll
    for (int a = 0; a < 8; a++) {
        float acc = ws[WS_G4 + a];
        #pragma unroll
        for (int s = 0; s < 8; s++) acc += xv[s] * ws[WS_G1 + a * 8 + s];
        #pragma unroll
        for (int c = 0; c < 6; c++) acc += uv[c] * ws[WS_G3 + a * 6 + c];
        h[a] = acc;
    }
    float y[5];
    #pragma unroll
    for (int q = 0; q < 5; q++) {
        float acc = ws[WS_BY + q];
        #pragma unroll
        for (int s = 0; s < 8; s++) acc += xv[s] * ws[WS_C2W + q * 8 + s];
        #pragma unroll
        for (int c = 0; c < 6; c++) acc += uv[c] * ws[WS_D22W + q * 6 + c];
        y[q] = acc;
    }

    // triangular tanh scan, two rows (2k, 2k+1) per pair-slot.
    // sv[p] for p<k holds finished w pairs; sv[k] holds (v0_2k, v0_2k+1).
    // DTT2 row 2k+1 pair p=k is (kappa*Dt[2k+1][2k], 0) — handled scalar.
    #pragma unroll
    for (int k = 0; k < 32; k++) {
        unsigned cur = sv[k];
        float acc = lo_f(cur);
        #pragma unroll
        for (int p = 0; p < k; p++) acc = dot2(wsu[WS_DTT2 + (2 * k) * 32 + p], sv[p], acc);
        float we = tanh_scaled(acc);

        float acc2 = hi_f(cur);
        #pragma unroll
        for (int p = 0; p < k; p++) acc2 = dot2(wsu[WS_DTT2 + (2 * k + 1) * 32 + p], sv[p], acc2);
        acc2 += lo_f(wsu[WS_DTT2 + (2 * k + 1) * 32 + k]) * we;   // j = 2k term
        float wo = tanh_scaled(acc2);

        sv[k] = pack_rn(we, wo);
    }

    // w contributions to outputs via packed dot2
    #pragma unroll
    for (int a = 0; a < 8; a++) {
        float acc = h[a];
        #pragma unroll
        for (int p = 0; p < 32; p++) acc = dot2(wsu[WS_G2P + a * 32 + p], sv[p], acc);
        h[a] = acc;
    }
    float4* hp = reinterpret_cast<float4*>(out + (size_t)t * 8);
    hp[0] = make_float4(h[0], h[1], h[2], h[3]);
    hp[1] = make_float4(h[4], h[5], h[6], h[7]);

    float* yp = out + (size_t)B * 8 + (size_t)t * 5;
    #pragma unroll
    for (int q = 0; q < 5; q++) {
        float acc = y[q];
        #pragma unroll
        for (int p = 0; p < 32; p++) acc = dot2(wsu[WS_D21P + q * 32 + p], sv[p], acc);
        yp[q] = acc;
    }
}

extern "C" void kernel_launch(void* const* d_in, const int* in_sizes, int n_in,
                              void* d_out, int out_size, void* d_ws, size_t ws_size,
                              hipStream_t stream) {
    const float* x      = (const float*)d_in[0];
    const float* u      = (const float*)d_in[1];
    const float* X      = (const float*)d_in[2];
    const float* calB2  = (const float*)d_in[3];
    const float* C2     = (const float*)d_in[4];
    const float* calD12 = (const float*)d_in[5];
    const float* D21    = (const float*)d_in[6];
    const float* D22    = (const float*)d_in[7];
    const float* Y1     = (const float*)d_in[8];
    const float* bias   = (const float*)d_in[9];
    float* ws  = (float*)d_ws;
    float* out = (float*)d_out;
    int B = in_sizes[0] / 8;

    k_gram  <<<(NH * NH + 255) / 256, 256, 0, stream>>>(X, ws);
    k_solve <<<1, 128, 0, stream>>>(Y1, ws);
    k_finish<<<1, 256, 0, stream>>>(calB2, calD12, C2, D21, D22, bias, ws);
    k_main  <<<(B + 255) / 256, 256, 0, stream>>>(x, u, ws, out, B);
}

// Round 12
// 71.562 us; speedup vs baseline: 3.2251x; 1.0880x over previous
//
#include <hip/hip_runtime.h>
#include <hip/hip_fp16.h>
#include <math.h>

// contracting REN forward. S=8, N=64, NU=6, NY=5, NH=80, B=524288.
// Outputs: hidden (B,8) then y (B,5), concatenated flat.
// R12: R11 (f16 pairs + v_dot2_f32_f16, fp32 accum, VGPR<=48) plus:
//  - dual accumulators per scan row (halved dependency chains)
//  - f16-packed G1/G3/C2/D22 matvecs
//  - fused solve+finish prep kernel

constexpr int NH = 80;

// ---- workspace layout (uint offsets unless noted) ----
constexpr int WS_DTT2 = 0;      // uint[64*32]  kappa*Dt[i] packed pairs (j<i else 0)
constexpr int WS_V0C  = 2048;   // uint[64*8]   per i: 4 C1 pairs, 3 D12 pairs, 1 zero
constexpr int WS_G2P  = 2560;   // uint[8*32]   (Einv@B1)[a] packed pairs
constexpr int WS_D21P = 2816;   // uint[5*32]   D21[q] packed pairs
constexpr int WS_G1P  = 2976;   // uint[8*4]    (Einv@F_)[a] packed pairs
constexpr int WS_G3P  = 3008;   // uint[8*3]    (Einv@calB_2)[a] packed pairs
constexpr int WS_C2P  = 3032;   // uint[5*4]    C2[q] packed pairs
constexpr int WS_D22P = 3052;   // uint[5*3]    D22[q] packed pairs
// float offsets
constexpr int WS_BWF  = 3072;   // float[64]    kappa*bw/Lambda
constexpr int WS_G4   = 3136;   // float[8]     Einv@bx
constexpr int WS_BY   = 3144;   // float[5]     by
// prep scratch (float offset)
constexpr int WS_H    = 4096;   // float[80*80]

__device__ __forceinline__ unsigned pack_rn(float a, float b) {
    unsigned lo = __half_as_ushort(__float2half(a));
    unsigned hi = __half_as_ushort(__float2half(b));
    return lo | (hi << 16);
}

typedef _Float16 h2 __attribute__((ext_vector_type(2)));

__device__ __forceinline__ float dot2(unsigned c, unsigned w, float acc) {
#if __has_builtin(__builtin_amdgcn_fdot2)
    return __builtin_amdgcn_fdot2(__builtin_bit_cast(h2, c),
                                  __builtin_bit_cast(h2, w), acc, false);
#else
    float out;
    asm("v_dot2_f32_f16 %0, %1, %2, %3" : "=v"(out) : "v"(c), "v"(w), "0"(acc));
    return out;
#endif
}
__device__ __forceinline__ float lo_f(unsigned u) { return (float)__builtin_bit_cast(h2, u).x; }
__device__ __forceinline__ float hi_f(unsigned u) { return (float)__builtin_bit_cast(h2, u).y; }

__global__ void k_gram(const float* __restrict__ X, float* __restrict__ ws) {
    int idx = blockIdx.x * blockDim.x + threadIdx.x;
    if (idx >= NH * NH) return;
    int a = idx / NH, b = idx % NH;
    float acc = (a == b) ? 1e-4f : 0.f;
    for (int k = 0; k < NH; k++) acc += X[k * NH + a] * X[k * NH + b];
    ws[WS_H + idx] = acc;
}

// fused: 8x8 Gauss-Jordan (LDS) + all constant folding/packing. One block, 256 thr.
__global__ void k_prep(const float* __restrict__ calB2,
                       const float* __restrict__ calD12,
                       const float* __restrict__ C2,
                       const float* __restrict__ D21,
                       const float* __restrict__ D22,
                       const float* __restrict__ Y1,
                       const float* __restrict__ bias,
                       float* ws) {
    __shared__ float sM[8][17];
    __shared__ int sPiv;
    __shared__ float srL[64];
    __shared__ float sEinv[64];
    int tid = threadIdx.x;  // 256
    const float* H = ws + WS_H;
    unsigned* wsu = (unsigned*)ws;
    const float KAPPA = 2.8853900817779268f;  // 2*log2(e)

    if (tid < 128) {
        int r = tid >> 4, c = tid & 15;
        sM[r][c] = (c < 8)
            ? 0.5f * (H[r * NH + c] + H[(72 + r) * NH + 72 + c] + Y1[r * 8 + c])
            : ((c - 8 == r) ? 1.f : 0.f);
    }
    if (tid >= 128 && tid < 192) srL[tid - 128] = 2.0f / H[(8 + tid - 128) * NH + 8 + tid - 128];
    __syncthreads();

    for (int p = 0; p < 8; p++) {
        if (tid == 0) {
            int pr = p; float best = fabsf(sM[p][p]);
            for (int r = p + 1; r < 8; r++) {
                float v = fabsf(sM[r][p]);
                if (v > best) { best = v; pr = r; }
            }
            sPiv = pr;
        }
        __syncthreads();
        int pr = sPiv;
        if (pr != p && tid < 16) { float tv = sM[p][tid]; sM[p][tid] = sM[pr][tid]; sM[pr][tid] = tv; }
        __syncthreads();
        if (tid < 16) {   // single wave: all lanes read pivot before any write
            float inv = 1.f / sM[p][p];
            sM[p][tid] *= inv;
        }
        __syncthreads();
        float f = 0.f, pc = 0.f;
        if (tid < 128) { int r = tid >> 4, c = tid & 15; f = sM[r][p]; pc = sM[p][c]; }
        __syncthreads();
        if (tid < 128) { int r = tid >> 4, c = tid & 15; if (r != p) sM[r][c] -= f * pc; }
        __syncthreads();
    }
    if (tid < 64) sEinv[tid] = sM[tid >> 3][8 + (tid & 7)];
    __syncthreads();

    // DTT2: packed kappa-scaled Dt rows (j<i else 0)
    for (int idx = tid; idx < 2048; idx += 256) {
        int i = idx >> 5, p = idx & 31;
        int j0 = 2 * p, j1 = 2 * p + 1;
        float f0 = (j0 < i) ? -KAPPA * H[(8 + i) * NH + 8 + j0] * srL[i] : 0.f;
        float f1 = (j1 < i) ? -KAPPA * H[(8 + i) * NH + 8 + j1] * srL[i] : 0.f;
        wsu[WS_DTT2 + idx] = pack_rn(f0, f1);
    }
    // V0C: per-row packed C1 (4 pairs) + D12 (3 pairs) + zero
    for (int idx = tid; idx < 512; idx += 256) {
        int i = idx >> 3, c = idx & 7;
        float f0 = 0.f, f1 = 0.f;
        if (c < 4) {
            f0 = -KAPPA * H[(8 + i) * NH + 2 * c] * srL[i];
            f1 = -KAPPA * H[(8 + i) * NH + 2 * c + 1] * srL[i];
        } else if (c < 7) {
            int d = 2 * (c - 4);
            f0 = KAPPA * calD12[i * 6 + d] * srL[i];
            f1 = KAPPA * calD12[i * 6 + d + 1] * srL[i];
        }
        wsu[WS_V0C + idx] = pack_rn(f0, f1);
    }
    // G2P = packed (Einv @ B1)
    if (tid < 256) {
        int a = tid >> 5, p = tid & 31;
        float g0 = 0.f, g1 = 0.f;
        for (int k = 0; k < 8; k++) {
            g0 += sEinv[a * 8 + k] * H[(72 + k) * NH + 8 + 2 * p];
            g1 += sEinv[a * 8 + k] * H[(72 + k) * NH + 8 + 2 * p + 1];
        }
        wsu[WS_G2P + tid] = pack_rn(g0, g1);
    }
    // D21P packed
    if (tid < 160) {
        int q = tid / 32, p = tid % 32;
        wsu[WS_D21P + tid] = pack_rn(D21[q * 64 + 2 * p], D21[q * 64 + 2 * p + 1]);
    }
    // G1P = packed (Einv @ F_)
    if (tid < 32) {
        int a = tid >> 2, c = tid & 3;
        float g0 = 0.f, g1 = 0.f;
        for (int k = 0; k < 8; k++) {
            g0 += sEinv[a * 8 + k] * H[(72 + k) * NH + 2 * c];
            g1 += sEinv[a * 8 + k] * H[(72 + k) * NH + 2 * c + 1];
        }
        wsu[WS_G1P + tid] = pack_rn(g0, g1);
    }
    // G3P = packed (Einv @ calB_2)
    if (tid < 24) {
        int a = tid / 3, c = tid % 3;
        float g0 = 0.f, g1 = 0.f;
        for (int k = 0; k < 8; k++) {
            g0 += sEinv[a * 8 + k] * calB2[k * 6 + 2 * c];
            g1 += sEinv[a * 8 + k] * calB2[k * 6 + 2 * c + 1];
        }
        wsu[WS_G3P + tid] = pack_rn(g0, g1);
    }
    // C2P / D22P packed copies
    if (tid < 20) {
        int q = tid >> 2, c = tid & 3;
        wsu[WS_C2P + tid] = pack_rn(C2[q * 8 + 2 * c], C2[q * 8 + 2 * c + 1]);
    }
    if (tid < 15) {
        int q = tid / 3, c = tid % 3;
        wsu[WS_D22P + tid] = pack_rn(D22[q * 6 + 2 * c], D22[q * 6 + 2 * c + 1]);
    }
    if (tid < 64) ws[WS_BWF + tid] = KAPPA * bias[8 + tid] * srL[tid];
    if (tid < 8) {
        float acc = 0.f;
        for (int k = 0; k < 8; k++) acc += sEinv[tid * 8 + k] * bias[k];
        ws[WS_G4 + tid] = acc;
    }
    if (tid < 5) ws[WS_BY + tid] = bias[72 + tid];
}

// acc already kappa-scaled: tanh(v) = 1 - 2/(1+2^q). No clamp needed:
// exp2(+big)=inf -> rcp=0 -> +1 ; exp2(-big)=0 -> rcp(1)=1 -> -1.
__device__ __forceinline__ float tanh_scaled(float q) {
    float e = __builtin_amdgcn_exp2f(q);
    return 1.f - 2.f * __builtin_amdgcn_rcpf(1.f + e);
}

__global__ __launch_bounds__(256) void k_main(
    const float* __restrict__ xg, const float* __restrict__ ug,
    const float* __restrict__ ws, float* __restrict__ out, int B)
{
    int t = blockIdx.x * blockDim.x + threadIdx.x;
    if (t >= B) return;

    const unsigned* wsu = (const unsigned*)ws;

    // load + pack x,u
    unsigned xh[4], uh[3];
    {
        const float4* xp = reinterpret_cast<const float4*>(xg + (size_t)t * 8);
        float4 a0 = xp[0], a1 = xp[1];
        xh[0] = pack_rn(a0.x, a0.y); xh[1] = pack_rn(a0.z, a0.w);
        xh[2] = pack_rn(a1.x, a1.y); xh[3] = pack_rn(a1.z, a1.w);
        const float2* up = reinterpret_cast<const float2*>(ug + (size_t)t * 6);
        float2 c0 = up[0], c1 = up[1], c2 = up[2];
        uh[0] = pack_rn(c0.x, c0.y); uh[1] = pack_rn(c1.x, c1.y); uh[2] = pack_rn(c2.x, c2.y);
    }

    // v0 pairs (kappa-scaled), packed into sv
    unsigned sv[32];
    #pragma unroll
    for (int k = 0; k < 32; k++) {
        float a0 = ws[WS_BWF + 2 * k];
        float a1 = ws[WS_BWF + 2 * k + 1];
        #pragma unroll
        for (int c = 0; c < 4; c++) {
            a0 = dot2(wsu[WS_V0C + (2 * k) * 8 + c],     xh[c], a0);
            a1 = dot2(wsu[WS_V0C + (2 * k + 1) * 8 + c], xh[c], a1);
        }
        #pragma unroll
        for (int c = 0; c < 3; c++) {
            a0 = dot2(wsu[WS_V0C + (2 * k) * 8 + 4 + c],     uh[c], a0);
            a1 = dot2(wsu[WS_V0C + (2 * k + 1) * 8 + 4 + c], uh[c], a1);
        }
        sv[k] = pack_rn(a0, a1);
    }

    // x/u parts of outputs (packed dot2)
    float h[8];
    #pragma unroll
    for (int a = 0; a < 8; a++) {
        float acc = ws[WS_G4 + a];
        #pragma unroll
        for (int c = 0; c < 4; c++) acc = dot2(wsu[WS_G1P + a * 4 + c], xh[c], acc);
        #pragma unroll
        for (int c = 0; c < 3; c++) acc = dot2(wsu[WS_G3P + a * 3 + c], uh[c], acc);
        h[a] = acc;
    }
    float y[5];
    #pragma unroll
    for (int q = 0; q < 5; q++) {
        float acc = ws[WS_BY + q];
        #pragma unroll
        for (int c = 0; c < 4; c++) acc = dot2(wsu[WS_C2P + q * 4 + c], xh[c], acc);
        #pragma unroll
        for (int c = 0; c < 3; c++) acc = dot2(wsu[WS_D22P + q * 3 + c], uh[c], acc);
        y[q] = acc;
    }

    // triangular tanh scan, two rows (2k, 2k+1) per pair-slot.
    // Dual accumulators per row halve the serial dot2 chain; the even-row
    // and odd-row p-chains are mutually independent (4 concurrent chains).
    #pragma unroll
    for (int k = 0; k < 32; k++) {
        unsigned cur = sv[k];

        float aE = lo_f(cur), aO = 0.f;
        #pragma unroll
        for (int p = 0; p < k; p += 2) aE = dot2(wsu[WS_DTT2 + (2 * k) * 32 + p], sv[p], aE);
        #pragma unroll
        for (int p = 1; p < k; p += 2) aO = dot2(wsu[WS_DTT2 + (2 * k) * 32 + p], sv[p], aO);
        float we = tanh_scaled(aE + aO);

        float bE = hi_f(cur), bO = 0.f;
        #pragma unroll
        for (int p = 0; p < k; p += 2) bE = dot2(wsu[WS_DTT2 + (2 * k + 1) * 32 + p], sv[p], bE);
        #pragma unroll
        for (int p = 1; p < k; p += 2) bO = dot2(wsu[WS_DTT2 + (2 * k + 1) * 32 + p], sv[p], bO);
        float wo = tanh_scaled(bE + bO + lo_f(wsu[WS_DTT2 + (2 * k + 1) * 32 + k]) * we);  // j=2k term

        sv[k] = pack_rn(we, wo);
    }

    // w contributions to outputs
    #pragma unroll
    for (int a = 0; a < 8; a++) {
        float acc = h[a];
        #pragma unroll
        for (int p = 0; p < 32; p++) acc = dot2(wsu[WS_G2P + a * 32 + p], sv[p], acc);
        h[a] = acc;
    }
    float4* hp = reinterpret_cast<float4*>(out + (size_t)t * 8);
    hp[0] = make_float4(h[0], h[1], h[2], h[3]);
    hp[1] = make_float4(h[4], h[5], h[6], h[7]);

    float* yp = out + (size_t)B * 8 + (size_t)t * 5;
    #pragma unroll
    for (int q = 0; q < 5; q++) {
        float acc = y[q];
        #pragma unroll
        for (int p = 0; p < 32; p++) acc = dot2(wsu[WS_D21P + q * 32 + p], sv[p], acc);
        yp[q] = acc;
    }
}

extern "C" void kernel_launch(void* const* d_in, const int* in_sizes, int n_in,
                              void* d_out, int out_size, void* d_ws, size_t ws_size,
                              hipStream_t stream) {
    const float* x      = (const float*)d_in[0];
    const float* u      = (const float*)d_in[1];
    const float* X      = (const float*)d_in[2];
    const float* calB2  = (const float*)d_in[3];
    const float* C2     = (const float*)d_in[4];
    const float* calD12 = (const float*)d_in[5];
    const float* D21    = (const float*)d_in[6];
    const float* D22    = (const float*)d_in[7];
    const float* Y1     = (const float*)d_in[8];
    const float* bias   = (const float*)d_in[9];
    float* ws  = (float*)d_ws;
    float* out = (float*)d_out;
    int B = in_sizes[0] / 8;

    k_gram<<<(NH * NH + 255) / 256, 256, 0, stream>>>(X, ws);
    k_prep<<<1, 256, 0, stream>>>(calB2, calD12, C2, D21, D22, Y1, bias, ws);
    k_main<<<(B + 255) / 256, 256, 0, stream>>>(x, u, ws, out, B);
}